// Round 6
// baseline (620.464 us; speedup 1.0000x reference)
//
#include <hip/hip_runtime.h>

constexpr int HID  = 20;
constexpr int NEXP = 16;
constexpr int CAP  = 20480;       // per-expert list capacity (avg 16384, sigma~124)
constexpr int NS   = 4;           // samples per thread in eval
constexpr int SPB  = 256 * NS;    // 1024 samples per eval block
constexpr int BPE  = CAP / SPB;   // 20 eval blocks per expert
constexpr int ROUNDS = 4;         // samples per lane in bucket kernel
constexpr int GSTRIDE = 16;       // ints between gcnt counters -> one 64B line each

// LDS float offsets for the single staged expert (all 16B-aligned)
constexpr int OFF_W1 = 0;     // [2][20]
constexpr int OFF_B1 = 40;    // [20]
constexpr int OFF_W2 = 60;    // [20][20]
constexpr int OFF_B2 = 460;
constexpr int OFF_W3 = 480;
constexpr int OFF_B3 = 880;
constexpr int OFF_W4 = 900;
constexpr int OFF_B4 = 1300;
constexpr int OFF_W5 = 1320;  // [20]
constexpr int OFF_B5 = 1340;  // [1]
constexpr int EFLOATS = 1344;

__device__ __forceinline__ float silu(float v) {
    float e = __expf(-v);
    return v * __builtin_amdgcn_rcpf(1.0f + e);
}

// region index per reference _region_mask: first cell lower bound inclusive,
// upper bounds inclusive, outside [-4,4] (or NaN) -> -1 (=> output 0)
__device__ __forceinline__ int cell_idx(float v) {
    if (!(v >= -4.0f))  return -1;   // also catches NaN
    if (v <= -0.674f)   return 0;
    if (v <= 0.0f)      return 1;
    if (v <= 0.674f)    return 2;
    if (v <= 4.0f)      return 3;
    return -1;
}

// ---------------- kernel 1: bucket samples into per-expert lists ----------------
// (unchanged from R4/R5 — measured ~1.8us incl. memset)
__global__ __launch_bounds__(256) void bucket_kernel(
    const float* __restrict__ x, int n_total,
    int* __restrict__ gcnt, int* __restrict__ lists,
    float* __restrict__ out)
{
    __shared__ int wcnt[4][NEXP];
    __shared__ int wbase[4][NEXP];

    const int tid  = threadIdx.x;
    const int lane = tid & 63;
    const int wv   = tid >> 6;
    const int base = blockIdx.x * (4 * ROUNDS * 64) + wv * (ROUNDS * 64);
    const unsigned long long lmask = (1ull << lane) - 1ull;
    const float2* x2 = reinterpret_cast<const float2*>(x);

    unsigned int epack = 0;
    int cnt[NEXP];
    #pragma unroll
    for (int k = 0; k < NEXP; ++k) cnt[k] = 0;

    #pragma unroll
    for (int r = 0; r < ROUNDS; ++r) {
        const int n = base + r * 64 + lane;
        int e = 17;
        if (n < n_total) {
            const float2 xv = x2[n];
            const int c = cell_idx(xv.x), rr = cell_idx(xv.y);
            e = ((c | rr) >= 0) ? (c * 4 + rr) : 16;
        }
        epack |= (unsigned)e << (r * 8);
        #pragma unroll
        for (int k = 0; k < NEXP; ++k)
            cnt[k] += (int)__popcll(__ballot(e == k));
    }

    if (lane == 0) {
        #pragma unroll
        for (int k = 0; k < NEXP; ++k) wcnt[wv][k] = cnt[k];
    }
    __syncthreads();

    if (tid < NEXP) {
        const int c0 = wcnt[0][tid], c1 = wcnt[1][tid],
                  c2 = wcnt[2][tid], c3 = wcnt[3][tid];
        const int tot = c0 + c1 + c2 + c3;
        int old = 0;
        if (tot) old = atomicAdd(&gcnt[tid * GSTRIDE], tot);
        wbase[0][tid] = old;
        wbase[1][tid] = old + c0;
        wbase[2][tid] = old + c0 + c1;
        wbase[3][tid] = old + c0 + c1 + c2;
    }
    __syncthreads();

    int wb[NEXP], roff[NEXP];
    #pragma unroll
    for (int k = 0; k < NEXP; ++k) { wb[k] = wbase[wv][k]; roff[k] = 0; }

    #pragma unroll
    for (int r = 0; r < ROUNDS; ++r) {
        const int e = (int)((epack >> (r * 8)) & 0xFFu);
        const int n = base + r * 64 + lane;
        int slot = -1;
        #pragma unroll
        for (int k = 0; k < NEXP; ++k) {
            const unsigned long long m = __ballot(e == k);
            if (e == k) slot = wb[k] + roff[k] + (int)__popcll(m & lmask);
            roff[k] += (int)__popcll(m);
        }
        if (e < NEXP)     lists[e * CAP + slot] = n;
        else if (e == 16) out[n] = 0.0f;
    }
}

// ---------------- kernel 2: eval, 1 expert/block, 4 samples/thread ----------------
// All register-array indices are macro-expanded literals -> SROA-scalarizable.

#define R20(X) X(0) X(1) X(2) X(3) X(4) X(5) X(6) X(7) X(8) X(9) \
               X(10) X(11) X(12) X(13) X(14) X(15) X(16) X(17) X(18) X(19)
#define R5M(X) X(0) X(1) X(2) X(3) X(4)

__global__ __launch_bounds__(256, 2) void eval_kernel(
    const float* __restrict__ x,
    const float* __restrict__ W1, const float* __restrict__ b1,
    const float* __restrict__ W2, const float* __restrict__ b2,
    const float* __restrict__ W3, const float* __restrict__ b3,
    const float* __restrict__ W4, const float* __restrict__ b4,
    const float* __restrict__ W5, const float* __restrict__ b5,
    const int* __restrict__ gcnt, const int* __restrict__ lists,
    float* __restrict__ out)
{
    __shared__ float Wl[EFLOATS];                 // 5.4 KB: one expert

    const int e     = blockIdx.x / BPE;           // SGPR-uniform expert id
    const int cbase = (blockIdx.x % BPE) * SPB;
    const int ce    = gcnt[e * GSTRIDE];          // scalar load
    if (cbase >= ce) return;                      // block-uniform early-exit

    const int tid = threadIdx.x;

    // ---- stage this expert's weights into LDS (float4) ----
    {
        float4*       d4 = reinterpret_cast<float4*>(Wl);
        const float4* s2 = reinterpret_cast<const float4*>(W2 + e * 400);
        const float4* s3 = reinterpret_cast<const float4*>(W3 + e * 400);
        const float4* s4 = reinterpret_cast<const float4*>(W4 + e * 400);
        if (tid < 100) {
            d4[OFF_W2/4 + tid] = s2[tid];
            d4[OFF_W3/4 + tid] = s3[tid];
            d4[OFF_W4/4 + tid] = s4[tid];
        } else if (tid < 110) {
            d4[OFF_W1/4 + (tid-100)] = reinterpret_cast<const float4*>(W1 + e*40)[tid-100];
        } else if (tid < 115) {
            d4[OFF_B1/4 + (tid-110)] = reinterpret_cast<const float4*>(b1 + e*20)[tid-110];
        } else if (tid < 120) {
            d4[OFF_B2/4 + (tid-115)] = reinterpret_cast<const float4*>(b2 + e*20)[tid-115];
        } else if (tid < 125) {
            d4[OFF_B3/4 + (tid-120)] = reinterpret_cast<const float4*>(b3 + e*20)[tid-120];
        } else if (tid < 130) {
            d4[OFF_B4/4 + (tid-125)] = reinterpret_cast<const float4*>(b4 + e*20)[tid-125];
        } else if (tid < 135) {
            d4[OFF_W5/4 + (tid-130)] = reinterpret_cast<const float4*>(W5 + e*20)[tid-130];
        } else if (tid == 135) {
            Wl[OFF_B5] = b5[e];
        }
    }

    // ---- gather 4 samples (issue before sync; loads are independent) ----
    const int lbase = e * CAP;
    const int s0 = cbase + tid, s1 = s0 + 256, s2i = s0 + 512, s3i = s0 + 768;
    const bool v0 = s0 < ce, v1 = s1 < ce, v2 = s2i < ce, v3 = s3i < ce;
    const int i0 = lists[lbase + (v0 ? s0  : cbase)];
    const int i1 = lists[lbase + (v1 ? s1  : cbase)];
    const int i2 = lists[lbase + (v2 ? s2i : cbase)];
    const int i3 = lists[lbase + (v3 ? s3i : cbase)];
    const float2* x2p = reinterpret_cast<const float2*>(x);
    const float2 xv0 = x2p[i0], xv1 = x2p[i1], xv2 = x2p[i2], xv3 = x2p[i3];

    __syncthreads();

    float h0[HID], h1[HID], h2[HID], h3[HID];
    float a0[HID], a1[HID], a2[HID], a3[HID];

    // ---- layer 1: 2 -> 20 (broadcast float4 LDS reads) ----
    {
        const float4* w1a = reinterpret_cast<const float4*>(Wl + OFF_W1);
        const float4* w1b = reinterpret_cast<const float4*>(Wl + OFF_W1 + 20);
        const float4* b1f = reinterpret_cast<const float4*>(Wl + OFF_B1);
#define L1E(j, wa, wb, bb) \
        h0[j] = silu(fmaf(xv0.x, wa, fmaf(xv0.y, wb, bb))); \
        h1[j] = silu(fmaf(xv1.x, wa, fmaf(xv1.y, wb, bb))); \
        h2[j] = silu(fmaf(xv2.x, wa, fmaf(xv2.y, wb, bb))); \
        h3[j] = silu(fmaf(xv3.x, wa, fmaf(xv3.y, wb, bb)));
#define L1Q(q) { const float4 wa_ = w1a[q], wb_ = w1b[q], bb_ = b1f[q]; \
        L1E(4*q+0, wa_.x, wb_.x, bb_.x) L1E(4*q+1, wa_.y, wb_.y, bb_.y) \
        L1E(4*q+2, wa_.z, wb_.z, bb_.z) L1E(4*q+3, wa_.w, wb_.w, bb_.w) }
        R5M(L1Q)
#undef L1Q
#undef L1E
    }

    // ---- layers 2..4: 20 -> 20, all indices literal ----
#define BINIT(j, bv) a0[j] = bv; a1[j] = bv; a2[j] = bv; a3[j] = bv;
#define BQ(q)  { const float4 b_ = Bf4[q]; \
        BINIT(4*q+0, b_.x) BINIT(4*q+1, b_.y) BINIT(4*q+2, b_.z) BINIT(4*q+3, b_.w) }
#define F1(j, wv) a0[j] = fmaf(x0_, wv, a0[j]); a1[j] = fmaf(x1_, wv, a1[j]); \
                  a2[j] = fmaf(x2_, wv, a2[j]); a3[j] = fmaf(x3_, wv, a3[j]);
#define KSTEP(k) { \
        const float4 w0_ = Wf4[5*(k)], w1_ = Wf4[5*(k)+1], w2_ = Wf4[5*(k)+2], \
                     w3_ = Wf4[5*(k)+3], w4_ = Wf4[5*(k)+4]; \
        const float x0_ = h0[k], x1_ = h1[k], x2_ = h2[k], x3_ = h3[k]; \
        F1(0,  w0_.x) F1(1,  w0_.y) F1(2,  w0_.z) F1(3,  w0_.w) \
        F1(4,  w1_.x) F1(5,  w1_.y) F1(6,  w1_.z) F1(7,  w1_.w) \
        F1(8,  w2_.x) F1(9,  w2_.y) F1(10, w2_.z) F1(11, w2_.w) \
        F1(12, w3_.x) F1(13, w3_.y) F1(14, w3_.z) F1(15, w3_.w) \
        F1(16, w4_.x) F1(17, w4_.y) F1(18, w4_.z) F1(19, w4_.w) }
#define SIL(j) h0[j] = silu(a0[j]); h1[j] = silu(a1[j]); \
               h2[j] = silu(a2[j]); h3[j] = silu(a3[j]);
#define LAYER20(WOFF, BOFF) { \
        const float4* Wf4 = reinterpret_cast<const float4*>(Wl + (WOFF)); \
        const float4* Bf4 = reinterpret_cast<const float4*>(Wl + (BOFF)); \
        R5M(BQ) R20(KSTEP) R20(SIL) }

    LAYER20(OFF_W2, OFF_B2)
    LAYER20(OFF_W3, OFF_B3)
    LAYER20(OFF_W4, OFF_B4)

#undef LAYER20
#undef SIL
#undef KSTEP
#undef F1
#undef BQ
#undef BINIT

    // ---- layer 5: 20 -> 1 ----
    float o0, o1, o2, o3;
    {
        const float bb = Wl[OFF_B5];
        o0 = bb; o1 = bb; o2 = bb; o3 = bb;
        const float4* w5f = reinterpret_cast<const float4*>(Wl + OFF_W5);
#define L5E(k, wv) o0 = fmaf(h0[k], wv, o0); o1 = fmaf(h1[k], wv, o1); \
                   o2 = fmaf(h2[k], wv, o2); o3 = fmaf(h3[k], wv, o3);
#define L5Q(q) { const float4 w_ = w5f[q]; \
        L5E(4*q+0, w_.x) L5E(4*q+1, w_.y) L5E(4*q+2, w_.z) L5E(4*q+3, w_.w) }
        R5M(L5Q)
#undef L5Q
#undef L5E
    }

    if (v0) out[i0] = o0;
    if (v1) out[i1] = o1;
    if (v2) out[i2] = o2;
    if (v3) out[i3] = o3;
}

extern "C" void kernel_launch(void* const* d_in, const int* in_sizes, int n_in,
                              void* d_out, int out_size, void* d_ws, size_t ws_size,
                              hipStream_t stream) {
    const float* x  = (const float*)d_in[0];
    const float* W1 = (const float*)d_in[1];
    const float* b1 = (const float*)d_in[2];
    const float* W2 = (const float*)d_in[3];
    const float* b2 = (const float*)d_in[4];
    const float* W3 = (const float*)d_in[5];
    const float* b3 = (const float*)d_in[6];
    const float* W4 = (const float*)d_in[7];
    const float* b4 = (const float*)d_in[8];
    const float* W5 = (const float*)d_in[9];
    const float* b5 = (const float*)d_in[10];
    float* out = (float*)d_out;

    const int n_total = in_sizes[0] / 2;          // 262144 samples

    int* gcnt  = (int*)d_ws;                      // 16 counters, 64B apart
    int* lists = (int*)d_ws + NEXP * GSTRIDE;     // 16 x CAP sample indices

    hipMemsetAsync(d_ws, 0, NEXP * GSTRIDE * sizeof(int), stream);

    const int k1_blocks = (n_total + (ROUNDS * 256) - 1) / (ROUNDS * 256); // 256
    hipLaunchKernelGGL(bucket_kernel, dim3(k1_blocks), dim3(256), 0, stream,
                       x, n_total, gcnt, lists, out);

    hipLaunchKernelGGL(eval_kernel, dim3(NEXP * BPE), dim3(256), 0, stream,
                       x, W1, b1, W2, b2, W3, b3, W4, b4, W5, b5,
                       gcnt, lists, out);
}

// Round 7
// 470.938 us; speedup vs baseline: 1.3175x; 1.3175x over previous
//
#include <hip/hip_runtime.h>

constexpr int HID  = 20;
constexpr int NEXP = 16;
constexpr int CAP  = 20480;       // per-expert list capacity (avg 16384, sigma~124)
constexpr int NS   = 4;           // samples per thread in eval (consecutive slots)
constexpr int SPB  = 256 * NS;    // 1024 samples per eval block
constexpr int BPE  = CAP / SPB;   // 20 chunk slots per expert
constexpr int ROUNDS = 4;         // samples per lane in bucket kernel
constexpr int GSTRIDE = 16;       // ints between gcnt counters -> one 64B line each

// LDS float offsets for the single staged expert (all 16B-aligned)
constexpr int OFF_W1 = 0;     // [2][20]
constexpr int OFF_B1 = 40;    // [20]
constexpr int OFF_W2 = 60;    // [20][20]
constexpr int OFF_B2 = 460;
constexpr int OFF_W3 = 480;
constexpr int OFF_B3 = 880;
constexpr int OFF_W4 = 900;
constexpr int OFF_B4 = 1300;
constexpr int OFF_W5 = 1320;  // [20]
constexpr int OFF_B5 = 1340;  // [1]
constexpr int EFLOATS = 1344;

__device__ __forceinline__ float silu(float v) {
    float e = __expf(-v);
    return v * __builtin_amdgcn_rcpf(1.0f + e);
}

// region index per reference _region_mask: first cell lower bound inclusive,
// upper bounds inclusive, outside [-4,4] (or NaN) -> -1 (=> output 0)
__device__ __forceinline__ int cell_idx(float v) {
    if (!(v >= -4.0f))  return -1;   // also catches NaN
    if (v <= -0.674f)   return 0;
    if (v <= 0.0f)      return 1;
    if (v <= 0.674f)    return 2;
    if (v <= 4.0f)      return 3;
    return -1;
}

// ---------------- kernel 1: bucket samples into per-expert lists ----------------
// (unchanged — measured ~1.8us incl. memset)
__global__ __launch_bounds__(256) void bucket_kernel(
    const float* __restrict__ x, int n_total,
    int* __restrict__ gcnt, int* __restrict__ lists,
    float* __restrict__ out)
{
    __shared__ int wcnt[4][NEXP];
    __shared__ int wbase[4][NEXP];

    const int tid  = threadIdx.x;
    const int lane = tid & 63;
    const int wv   = tid >> 6;
    const int base = blockIdx.x * (4 * ROUNDS * 64) + wv * (ROUNDS * 64);
    const unsigned long long lmask = (1ull << lane) - 1ull;
    const float2* x2 = reinterpret_cast<const float2*>(x);

    unsigned int epack = 0;
    int cnt[NEXP];
    #pragma unroll
    for (int k = 0; k < NEXP; ++k) cnt[k] = 0;

    #pragma unroll
    for (int r = 0; r < ROUNDS; ++r) {
        const int n = base + r * 64 + lane;
        int e = 17;
        if (n < n_total) {
            const float2 xv = x2[n];
            const int c = cell_idx(xv.x), rr = cell_idx(xv.y);
            e = ((c | rr) >= 0) ? (c * 4 + rr) : 16;
        }
        epack |= (unsigned)e << (r * 8);
        #pragma unroll
        for (int k = 0; k < NEXP; ++k)
            cnt[k] += (int)__popcll(__ballot(e == k));
    }

    if (lane == 0) {
        #pragma unroll
        for (int k = 0; k < NEXP; ++k) wcnt[wv][k] = cnt[k];
    }
    __syncthreads();

    if (tid < NEXP) {
        const int c0 = wcnt[0][tid], c1 = wcnt[1][tid],
                  c2 = wcnt[2][tid], c3 = wcnt[3][tid];
        const int tot = c0 + c1 + c2 + c3;
        int old = 0;
        if (tot) old = atomicAdd(&gcnt[tid * GSTRIDE], tot);
        wbase[0][tid] = old;
        wbase[1][tid] = old + c0;
        wbase[2][tid] = old + c0 + c1;
        wbase[3][tid] = old + c0 + c1 + c2;
    }
    __syncthreads();

    int wb[NEXP], roff[NEXP];
    #pragma unroll
    for (int k = 0; k < NEXP; ++k) { wb[k] = wbase[wv][k]; roff[k] = 0; }

    #pragma unroll
    for (int r = 0; r < ROUNDS; ++r) {
        const int e = (int)((epack >> (r * 8)) & 0xFFu);
        const int n = base + r * 64 + lane;
        int slot = -1;
        #pragma unroll
        for (int k = 0; k < NEXP; ++k) {
            const unsigned long long m = __ballot(e == k);
            if (e == k) slot = wb[k] + roff[k] + (int)__popcll(m & lmask);
            roff[k] += (int)__popcll(m);
        }
        if (e < NEXP)     lists[e * CAP + slot] = n;
        else if (e == 16) out[n] = 0.0f;
    }
}

// ---------------- kernel 2: eval, 1 expert/block, 4 consecutive samples/thread ----
// All register-array indices are macro-expanded literals -> SROA-scalarizable.
// amdgpu_waves_per_eu(2,2): allocator targets exactly 2 waves/EU -> up to 256 VGPR,
// no spill (R6 failure mode: allocator chose 128 VGPR -> 628MB scratch traffic).

#define R20(X) X(0) X(1) X(2) X(3) X(4) X(5) X(6) X(7) X(8) X(9) \
               X(10) X(11) X(12) X(13) X(14) X(15) X(16) X(17) X(18) X(19)
#define R5M(X) X(0) X(1) X(2) X(3) X(4)

__global__ __launch_bounds__(256)
__attribute__((amdgpu_waves_per_eu(2, 2)))
void eval_kernel(
    const float* __restrict__ x,
    const float* __restrict__ W1, const float* __restrict__ b1,
    const float* __restrict__ W2, const float* __restrict__ b2,
    const float* __restrict__ W3, const float* __restrict__ b3,
    const float* __restrict__ W4, const float* __restrict__ b4,
    const float* __restrict__ W5, const float* __restrict__ b5,
    const int* __restrict__ gcnt, const int* __restrict__ lists,
    float* __restrict__ out)
{
    __shared__ float Wl[EFLOATS];                 // 5.4 KB: one expert

    // j-major mapping: full chunks (j<16) are block ids 0..255 -> 1 per CU;
    // partial tails (j=16) are ids 256..271 -> the only doubled-up CUs.
    const int e     = blockIdx.x & 15;            // SGPR-uniform expert id
    const int j     = blockIdx.x >> 4;            // chunk within expert
    const int cbase = j * SPB;
    const int ce    = gcnt[e * GSTRIDE];          // scalar load
    if (cbase >= ce) return;                      // block-uniform early-exit

    const int tid = threadIdx.x;

    // ---- stage this expert's weights into LDS (float4), all threads present ----
    {
        float4*       d4 = reinterpret_cast<float4*>(Wl);
        const float4* s2 = reinterpret_cast<const float4*>(W2 + e * 400);
        const float4* s3 = reinterpret_cast<const float4*>(W3 + e * 400);
        const float4* s4 = reinterpret_cast<const float4*>(W4 + e * 400);
        if (tid < 100) {
            d4[OFF_W2/4 + tid] = s2[tid];
            d4[OFF_W3/4 + tid] = s3[tid];
            d4[OFF_W4/4 + tid] = s4[tid];
        } else if (tid < 110) {
            d4[OFF_W1/4 + (tid-100)] = reinterpret_cast<const float4*>(W1 + e*40)[tid-100];
        } else if (tid < 115) {
            d4[OFF_B1/4 + (tid-110)] = reinterpret_cast<const float4*>(b1 + e*20)[tid-110];
        } else if (tid < 120) {
            d4[OFF_B2/4 + (tid-115)] = reinterpret_cast<const float4*>(b2 + e*20)[tid-115];
        } else if (tid < 125) {
            d4[OFF_B3/4 + (tid-120)] = reinterpret_cast<const float4*>(b3 + e*20)[tid-120];
        } else if (tid < 130) {
            d4[OFF_B4/4 + (tid-125)] = reinterpret_cast<const float4*>(b4 + e*20)[tid-125];
        } else if (tid < 135) {
            d4[OFF_W5/4 + (tid-130)] = reinterpret_cast<const float4*>(W5 + e*20)[tid-130];
        } else if (tid == 135) {
            Wl[OFF_B5] = b5[e];
        }
    }
    __syncthreads();

    // ---- consecutive 4-slot group per thread; whole-thread early exit ----
    const int s0 = cbase + tid * NS;
    if (s0 >= ce) return;                         // tail waves retire early

    const int4 iv = *reinterpret_cast<const int4*>(&lists[e * CAP + s0]); // 16B aligned
    const bool v1 = s0 + 1 < ce, v2 = s0 + 2 < ce, v3 = s0 + 3 < ce;
    const int i0 = iv.x;                          // s0 < ce guaranteed valid
    const int i1 = v1 ? iv.y : i0;                // clamp: never deref poisoned slots
    const int i2 = v2 ? iv.z : i0;
    const int i3 = v3 ? iv.w : i0;

    const float2* x2p = reinterpret_cast<const float2*>(x);
    const float2 xv0 = x2p[i0], xv1 = x2p[i1], xv2 = x2p[i2], xv3 = x2p[i3];

    float h0[HID], h1[HID], h2[HID], h3[HID];
    float a0[HID], a1[HID], a2[HID], a3[HID];

    // ---- layer 1: 2 -> 20 (broadcast float4 LDS reads) ----
    {
        const float4* w1a = reinterpret_cast<const float4*>(Wl + OFF_W1);
        const float4* w1b = reinterpret_cast<const float4*>(Wl + OFF_W1 + 20);
        const float4* b1f = reinterpret_cast<const float4*>(Wl + OFF_B1);
#define L1E(j, wa, wb, bb) \
        h0[j] = silu(fmaf(xv0.x, wa, fmaf(xv0.y, wb, bb))); \
        h1[j] = silu(fmaf(xv1.x, wa, fmaf(xv1.y, wb, bb))); \
        h2[j] = silu(fmaf(xv2.x, wa, fmaf(xv2.y, wb, bb))); \
        h3[j] = silu(fmaf(xv3.x, wa, fmaf(xv3.y, wb, bb)));
#define L1Q(q) { const float4 wa_ = w1a[q], wb_ = w1b[q], bb_ = b1f[q]; \
        L1E(4*q+0, wa_.x, wb_.x, bb_.x) L1E(4*q+1, wa_.y, wb_.y, bb_.y) \
        L1E(4*q+2, wa_.z, wb_.z, bb_.z) L1E(4*q+3, wa_.w, wb_.w, bb_.w) }
        R5M(L1Q)
#undef L1Q
#undef L1E
    }

    // ---- layers 2..4: 20 -> 20, all indices literal ----
#define BINIT(j, bv) a0[j] = bv; a1[j] = bv; a2[j] = bv; a3[j] = bv;
#define BQ(q)  { const float4 b_ = Bf4[q]; \
        BINIT(4*q+0, b_.x) BINIT(4*q+1, b_.y) BINIT(4*q+2, b_.z) BINIT(4*q+3, b_.w) }
#define F1(j, wv) a0[j] = fmaf(x0_, wv, a0[j]); a1[j] = fmaf(x1_, wv, a1[j]); \
                  a2[j] = fmaf(x2_, wv, a2[j]); a3[j] = fmaf(x3_, wv, a3[j]);
#define KSTEP(k) { \
        const float4 w0_ = Wf4[5*(k)], w1_ = Wf4[5*(k)+1], w2_ = Wf4[5*(k)+2], \
                     w3_ = Wf4[5*(k)+3], w4_ = Wf4[5*(k)+4]; \
        const float x0_ = h0[k], x1_ = h1[k], x2_ = h2[k], x3_ = h3[k]; \
        F1(0,  w0_.x) F1(1,  w0_.y) F1(2,  w0_.z) F1(3,  w0_.w) \
        F1(4,  w1_.x) F1(5,  w1_.y) F1(6,  w1_.z) F1(7,  w1_.w) \
        F1(8,  w2_.x) F1(9,  w2_.y) F1(10, w2_.z) F1(11, w2_.w) \
        F1(12, w3_.x) F1(13, w3_.y) F1(14, w3_.z) F1(15, w3_.w) \
        F1(16, w4_.x) F1(17, w4_.y) F1(18, w4_.z) F1(19, w4_.w) }
#define SIL(j) h0[j] = silu(a0[j]); h1[j] = silu(a1[j]); \
               h2[j] = silu(a2[j]); h3[j] = silu(a3[j]);
#define LAYER20(WOFF, BOFF) { \
        const float4* Wf4 = reinterpret_cast<const float4*>(Wl + (WOFF)); \
        const float4* Bf4 = reinterpret_cast<const float4*>(Wl + (BOFF)); \
        R5M(BQ) R20(KSTEP) R20(SIL) }

    LAYER20(OFF_W2, OFF_B2)
    LAYER20(OFF_W3, OFF_B3)
    LAYER20(OFF_W4, OFF_B4)

#undef LAYER20
#undef SIL
#undef KSTEP
#undef F1
#undef BQ
#undef BINIT

    // ---- layer 5: 20 -> 1 ----
    float o0, o1, o2, o3;
    {
        const float bb = Wl[OFF_B5];
        o0 = bb; o1 = bb; o2 = bb; o3 = bb;
        const float4* w5f = reinterpret_cast<const float4*>(Wl + OFF_W5);
#define L5E(k, wv) o0 = fmaf(h0[k], wv, o0); o1 = fmaf(h1[k], wv, o1); \
                   o2 = fmaf(h2[k], wv, o2); o3 = fmaf(h3[k], wv, o3);
#define L5Q(q) { const float4 w_ = w5f[q]; \
        L5E(4*q+0, w_.x) L5E(4*q+1, w_.y) L5E(4*q+2, w_.z) L5E(4*q+3, w_.w) }
        R5M(L5Q)
#undef L5Q
#undef L5E
    }

    out[i0] = o0;                 // s0 valid by construction
    if (v1) out[i1] = o1;
    if (v2) out[i2] = o2;
    if (v3) out[i3] = o3;
}

extern "C" void kernel_launch(void* const* d_in, const int* in_sizes, int n_in,
                              void* d_out, int out_size, void* d_ws, size_t ws_size,
                              hipStream_t stream) {
    const float* x  = (const float*)d_in[0];
    const float* W1 = (const float*)d_in[1];
    const float* b1 = (const float*)d_in[2];
    const float* W2 = (const float*)d_in[3];
    const float* b2 = (const float*)d_in[4];
    const float* W3 = (const float*)d_in[5];
    const float* b3 = (const float*)d_in[6];
    const float* W4 = (const float*)d_in[7];
    const float* b4 = (const float*)d_in[8];
    const float* W5 = (const float*)d_in[9];
    const float* b5 = (const float*)d_in[10];
    float* out = (float*)d_out;

    const int n_total = in_sizes[0] / 2;          // 262144 samples

    int* gcnt  = (int*)d_ws;                      // 16 counters, 64B apart
    int* lists = (int*)d_ws + NEXP * GSTRIDE;     // 16 x CAP sample indices

    hipMemsetAsync(d_ws, 0, NEXP * GSTRIDE * sizeof(int), stream);

    const int k1_blocks = (n_total + (ROUNDS * 256) - 1) / (ROUNDS * 256); // 256
    hipLaunchKernelGGL(bucket_kernel, dim3(k1_blocks), dim3(256), 0, stream,
                       x, n_total, gcnt, lists, out);

    hipLaunchKernelGGL(eval_kernel, dim3(NEXP * BPE), dim3(256), 0, stream,
                       x, W1, b1, W2, b2, W3, b3, W4, b4, W5, b5,
                       gcnt, lists, out);
}

// Round 9
// 81.539 us; speedup vs baseline: 7.6094x; 5.7756x over previous
//
#include <hip/hip_runtime.h>

constexpr int HID  = 20;
constexpr int NEXP = 16;
constexpr int CAP  = 20480;       // per-expert list capacity (avg 16384, sigma~124)
constexpr int NS   = 2;           // samples per thread in eval (consecutive slots)
constexpr int SPB  = 256 * NS;    // 512 samples per eval block
constexpr int BPE  = CAP / SPB;   // 40 chunk slots per expert
constexpr int ROUNDS = 4;         // samples per lane in bucket kernel
constexpr int GSTRIDE = 16;       // ints between gcnt counters -> one 64B line each

__device__ __forceinline__ float silu(float v) {
    float e = __expf(-v);
    return v * __builtin_amdgcn_rcpf(1.0f + e);
}

// region index per reference _region_mask: first cell lower bound inclusive,
// upper bounds inclusive, outside [-4,4] (or NaN) -> -1 (=> output 0)
__device__ __forceinline__ int cell_idx(float v) {
    if (!(v >= -4.0f))  return -1;   // also catches NaN
    if (v <= -0.674f)   return 0;
    if (v <= 0.0f)      return 1;
    if (v <= 0.674f)    return 2;
    if (v <= 4.0f)      return 3;
    return -1;
}

// ---------------- kernel 1: bucket samples into per-expert lists ----------------
// (unchanged — measured ~1.8us incl. memset)
__global__ __launch_bounds__(256) void bucket_kernel(
    const float* __restrict__ x, int n_total,
    int* __restrict__ gcnt, int* __restrict__ lists,
    float* __restrict__ out)
{
    __shared__ int wcnt[4][NEXP];
    __shared__ int wbase[4][NEXP];

    const int tid  = threadIdx.x;
    const int lane = tid & 63;
    const int wv   = tid >> 6;
    const int base = blockIdx.x * (4 * ROUNDS * 64) + wv * (ROUNDS * 64);
    const unsigned long long lmask = (1ull << lane) - 1ull;
    const float2* x2 = reinterpret_cast<const float2*>(x);

    unsigned int epack = 0;
    int cnt[NEXP];
    #pragma unroll
    for (int k = 0; k < NEXP; ++k) cnt[k] = 0;

    #pragma unroll
    for (int r = 0; r < ROUNDS; ++r) {
        const int n = base + r * 64 + lane;
        int e = 17;
        if (n < n_total) {
            const float2 xv = x2[n];
            const int c = cell_idx(xv.x), rr = cell_idx(xv.y);
            e = ((c | rr) >= 0) ? (c * 4 + rr) : 16;
        }
        epack |= (unsigned)e << (r * 8);
        #pragma unroll
        for (int k = 0; k < NEXP; ++k)
            cnt[k] += (int)__popcll(__ballot(e == k));
    }

    if (lane == 0) {
        #pragma unroll
        for (int k = 0; k < NEXP; ++k) wcnt[wv][k] = cnt[k];
    }
    __syncthreads();

    if (tid < NEXP) {
        const int c0 = wcnt[0][tid], c1 = wcnt[1][tid],
                  c2 = wcnt[2][tid], c3 = wcnt[3][tid];
        const int tot = c0 + c1 + c2 + c3;
        int old = 0;
        if (tot) old = atomicAdd(&gcnt[tid * GSTRIDE], tot);
        wbase[0][tid] = old;
        wbase[1][tid] = old + c0;
        wbase[2][tid] = old + c0 + c1;
        wbase[3][tid] = old + c0 + c1 + c2;
    }
    __syncthreads();

    int wb[NEXP], roff[NEXP];
    #pragma unroll
    for (int k = 0; k < NEXP; ++k) { wb[k] = wbase[wv][k]; roff[k] = 0; }

    #pragma unroll
    for (int r = 0; r < ROUNDS; ++r) {
        const int e = (int)((epack >> (r * 8)) & 0xFFu);
        const int n = base + r * 64 + lane;
        int slot = -1;
        #pragma unroll
        for (int k = 0; k < NEXP; ++k) {
            const unsigned long long m = __ballot(e == k);
            if (e == k) slot = wb[k] + roff[k] + (int)__popcll(m & lmask);
            roff[k] += (int)__popcll(m);
        }
        if (e < NEXP)     lists[e * CAP + slot] = n;
        else if (e == 16) out[n] = 0.0f;
    }
}

// ---------------- kernel 2: eval, 1 expert/block, 2 samples/thread ----------------
// Expert id is blockIdx-derived -> wave-uniform -> weight reads from read-only
// global memory become s_load + v_fmac(v, s, v): NO LDS, no vector weight loads.
// All register-array indices macro-expanded literals (SROA-proven in R6/R7).
// NS=2 register demand ~100 VGPR < the allocator's 128 cap -> no spill.
// NOTE: two repeat macros (R20 outer, R20B inner) — the preprocessor will not
// re-expand a macro recursively inside its own expansion (R8 compile failure).

#define R20(X) X(0) X(1) X(2) X(3) X(4) X(5) X(6) X(7) X(8) X(9) \
               X(10) X(11) X(12) X(13) X(14) X(15) X(16) X(17) X(18) X(19)
#define R20B(X) X(0) X(1) X(2) X(3) X(4) X(5) X(6) X(7) X(8) X(9) \
                X(10) X(11) X(12) X(13) X(14) X(15) X(16) X(17) X(18) X(19)

__global__ __launch_bounds__(256) void eval_kernel(
    const float* __restrict__ x,
    const float* __restrict__ W1, const float* __restrict__ b1,
    const float* __restrict__ W2, const float* __restrict__ b2,
    const float* __restrict__ W3, const float* __restrict__ b3,
    const float* __restrict__ W4, const float* __restrict__ b4,
    const float* __restrict__ W5, const float* __restrict__ b5,
    const int* __restrict__ gcnt, const int* __restrict__ lists,
    float* __restrict__ out)
{
    // j-major: full chunks spread 1-per-CU first; tails are the only doubled CUs
    const int e     = blockIdx.x & 15;            // SGPR-uniform expert id
    const int j     = blockIdx.x >> 4;            // chunk within expert
    const int cbase = j * SPB;
    const int ce    = gcnt[e * GSTRIDE];          // scalar load
    if (cbase >= ce) return;                      // block-uniform early-exit

    const int s0 = cbase + threadIdx.x * NS;
    if (s0 >= ce) return;                         // tail waves retire early

    const int2 iv = *reinterpret_cast<const int2*>(&lists[e * CAP + s0]); // 8B aligned
    const bool v1 = s0 + 1 < ce;
    const int i0 = iv.x;                          // s0 < ce guaranteed valid
    const int i1 = v1 ? iv.y : i0;                // never deref poisoned slots

    const float2* x2p = reinterpret_cast<const float2*>(x);
    const float2 xv0 = x2p[i0], xv1 = x2p[i1];

    // uniform weight base pointers (scalar address arithmetic)
    const float* w1g = W1 + e * (2 * HID);
    const float* b1g = b1 + e * HID;
    const float* w2g = W2 + e * (HID * HID);
    const float* b2g = b2 + e * HID;
    const float* w3g = W3 + e * (HID * HID);
    const float* b3g = b3 + e * HID;
    const float* w4g = W4 + e * (HID * HID);
    const float* b4g = b4 + e * HID;
    const float* w5g = W5 + e * HID;
    const float* b5g = b5 + e;

    float h0[HID], h1[HID];
    float a0[HID], a1[HID];

    // ---- layer 1: 2 -> 20 ----
#define L1E(j) { const float wa_ = w1g[j], wb_ = w1g[HID + (j)], bb_ = b1g[j]; \
        h0[j] = silu(fmaf(xv0.x, wa_, fmaf(xv0.y, wb_, bb_))); \
        h1[j] = silu(fmaf(xv1.x, wa_, fmaf(xv1.y, wb_, bb_))); }
    R20(L1E)
#undef L1E

    // ---- layers 2..4: 20 -> 20, weights as scalar operands ----
#define BINIT(j) { const float b_ = Bg_[j]; a0[j] = b_; a1[j] = b_; }
#define F1(j) { const float w_ = Wg_[20 * KK + (j)]; \
        a0[j] = fmaf(x0_, w_, a0[j]); a1[j] = fmaf(x1_, w_, a1[j]); }
#define KSTEP(k) { constexpr int KK = (k); \
        const float x0_ = h0[k], x1_ = h1[k]; \
        R20B(F1) }
#define SIL(j) { h0[j] = silu(a0[j]); h1[j] = silu(a1[j]); }
#define LAYER20(Wg, Bg) { \
        const float* __restrict__ Wg_ = (Wg); \
        const float* __restrict__ Bg_ = (Bg); \
        R20(BINIT) R20(KSTEP) R20(SIL) }

    LAYER20(w2g, b2g)
    LAYER20(w3g, b3g)
    LAYER20(w4g, b4g)

#undef LAYER20
#undef SIL
#undef KSTEP
#undef F1
#undef BINIT

    // ---- layer 5: 20 -> 1 ----
    float o0 = b5g[0], o1 = o0;
#define L5E(k) { const float w_ = w5g[k]; \
        o0 = fmaf(h0[k], w_, o0); o1 = fmaf(h1[k], w_, o1); }
    R20(L5E)
#undef L5E

    out[i0] = o0;                 // s0 valid by construction
    if (v1) out[i1] = o1;
}

extern "C" void kernel_launch(void* const* d_in, const int* in_sizes, int n_in,
                              void* d_out, int out_size, void* d_ws, size_t ws_size,
                              hipStream_t stream) {
    const float* x  = (const float*)d_in[0];
    const float* W1 = (const float*)d_in[1];
    const float* b1 = (const float*)d_in[2];
    const float* W2 = (const float*)d_in[3];
    const float* b2 = (const float*)d_in[4];
    const float* W3 = (const float*)d_in[5];
    const float* b3 = (const float*)d_in[6];
    const float* W4 = (const float*)d_in[7];
    const float* b4 = (const float*)d_in[8];
    const float* W5 = (const float*)d_in[9];
    const float* b5 = (const float*)d_in[10];
    float* out = (float*)d_out;

    const int n_total = in_sizes[0] / 2;          // 262144 samples

    int* gcnt  = (int*)d_ws;                      // 16 counters, 64B apart
    int* lists = (int*)d_ws + NEXP * GSTRIDE;     // 16 x CAP sample indices

    hipMemsetAsync(d_ws, 0, NEXP * GSTRIDE * sizeof(int), stream);

    const int k1_blocks = (n_total + (ROUNDS * 256) - 1) / (ROUNDS * 256); // 256
    hipLaunchKernelGGL(bucket_kernel, dim3(k1_blocks), dim3(256), 0, stream,
                       x, n_total, gcnt, lists, out);

    hipLaunchKernelGGL(eval_kernel, dim3(NEXP * BPE), dim3(256), 0, stream,
                       x, W1, b1, W2, b2, W3, b3, W4, b4, W5, b5,
                       gcnt, lists, out);
}